// Round 1
// baseline (506.369 us; speedup 1.0000x reference)
//
#include <hip/hip_runtime.h>

#define NDRUG 591
#define FDIM 1024
#define NEDGE 120000
#define HSTRIDE 605184      // 591*1024
#define ASTRIDE 349281      // 591*591

// ---------------- init: zero A, deg=1 (self loop), zero pool acc ----------------
__global__ void init_kernel(float* deg, float* Amat, float* scal) {
    int i = blockIdx.x * blockDim.x + threadIdx.x;
    const int ATOT = 3 * ASTRIDE;
    if (i < ATOT) Amat[i] = 0.f;
    if (i < 3 * NDRUG) deg[i] = 1.0f;   // self-loop weight
    if (i < 16) scal[i] = 0.f;
}

// ---------------- degree accumulation ----------------
__global__ void deg_kernel(const int* e_t, const float* w_t,
                           const int* e_s, const float* w_s,
                           const int* e_g, const float* w_g, float* deg) {
    int i = blockIdx.x * blockDim.x + threadIdx.x;
    if (i >= 3 * NEDGE) return;
    int g = i / NEDGE, e = i - g * NEDGE;
    const int*   E_ = (g == 0) ? e_t : (g == 1) ? e_s : e_g;
    const float* W_ = (g == 0) ? w_t : (g == 1) ? w_s : w_g;
    int dst = E_[NEDGE + e];
    atomicAdd(deg + g * NDRUG + dst, W_[e]);
}

__global__ void dinv_kernel(const float* deg, float* dinv) {
    int i = blockIdx.x * blockDim.x + threadIdx.x;
    if (i >= 3 * NDRUG) return;
    float d = deg[i];
    dinv[i] = (d > 0.f) ? rsqrtf(d) : 0.f;
}

// ---------------- dense normalized adjacency build ----------------
__global__ void abuild_kernel(const int* e_t, const float* w_t,
                              const int* e_s, const float* w_s,
                              const int* e_g, const float* w_g,
                              const float* dinv, float* Amat) {
    int i = blockIdx.x * blockDim.x + threadIdx.x;
    const int PER = NEDGE + NDRUG;
    if (i >= 3 * PER) return;
    int g = i / PER, r = i - g * PER;
    const float* dv = dinv + g * NDRUG;
    float* Ag = Amat + (long)g * ASTRIDE;
    if (r < NEDGE) {
        const int*   E_ = (g == 0) ? e_t : (g == 1) ? e_s : e_g;
        const float* W_ = (g == 0) ? w_t : (g == 1) ? w_s : w_g;
        int src = E_[r];
        int dst = E_[NEDGE + r];
        atomicAdd(Ag + dst * NDRUG + src, dv[src] * W_[r] * dv[dst]);
    } else {
        int n = r - NEDGE;
        atomicAdd(Ag + n * NDRUG + n, dv[n] * dv[n]);   // self loop, norm = dinv^2
    }
}

// ---------------- fp32 tiled GEMM: C = A@B (+bias, relu) ----------------
// 64x64 tile, BK=16, 256 threads, 4x4 per thread. Batched over blockIdx.z (3 graphs).
template <bool EPI>
__global__ __launch_bounds__(256) void gemm_kernel(
    const float* A0, const float* A1, const float* A2, int lda,
    const float* B0, const float* B1, const float* B2,
    const float* bb0, const float* bb1, const float* bb2,
    float* C0, float* C1, float* C2,
    int M, int K, int N)
{
    __shared__ float Ast[16][64];   // transposed A tile: [k][m]
    __shared__ float Bs[16][64];    // [k][n]
    int g = blockIdx.z;
    const float* A = (g == 0) ? A0 : (g == 1) ? A1 : A2;
    const float* B = (g == 0) ? B0 : (g == 1) ? B1 : B2;
    const float* bias = (g == 0) ? bb0 : (g == 1) ? bb1 : bb2;
    float* C = (g == 0) ? C0 : (g == 1) ? C1 : C2;

    int n0 = blockIdx.x * 64, m0 = blockIdx.y * 64;
    int tid = threadIdx.x;
    int ty = tid >> 4, tx = tid & 15;
    int ar = tid >> 2;            // 0..63 (row within A tile)
    int ac = (tid & 3) * 4;       // 0,4,8,12 (k within tile)
    int br = tid >> 4;            // 0..15 (k within B tile)
    int bc = (tid & 15) * 4;      // 0..60 (col within tile)
    const bool lda_vec = ((lda & 3) == 0);

    float c[4][4];
#pragma unroll
    for (int i = 0; i < 4; i++)
#pragma unroll
        for (int j = 0; j < 4; j++) c[i][j] = 0.f;

    for (int k0 = 0; k0 < K; k0 += 16) {
        // A tile -> Ast (transposed)
        {
            int gm = m0 + ar;
            float v0 = 0.f, v1 = 0.f, v2 = 0.f, v3 = 0.f;
            if (gm < M) {
                const float* ap = A + (long)gm * lda + k0 + ac;
                if (lda_vec && (k0 + ac + 3 < K)) {
                    float4 v = *(const float4*)ap;
                    v0 = v.x; v1 = v.y; v2 = v.z; v3 = v.w;
                } else {
                    if (k0 + ac + 0 < K) v0 = ap[0];
                    if (k0 + ac + 1 < K) v1 = ap[1];
                    if (k0 + ac + 2 < K) v2 = ap[2];
                    if (k0 + ac + 3 < K) v3 = ap[3];
                }
            }
            Ast[ac + 0][ar] = v0;
            Ast[ac + 1][ar] = v1;
            Ast[ac + 2][ar] = v2;
            Ast[ac + 3][ar] = v3;
        }
        // B tile
        {
            int gk = k0 + br;
            float4 v = make_float4(0.f, 0.f, 0.f, 0.f);
            if (gk < K) v = *(const float4*)(B + (long)gk * N + n0 + bc);
            *(float4*)&Bs[br][bc] = v;
        }
        __syncthreads();
#pragma unroll
        for (int kk = 0; kk < 16; ++kk) {
            float4 av = *(const float4*)&Ast[kk][ty * 4];
            float4 bv = *(const float4*)&Bs[kk][tx * 4];
            float a_[4] = {av.x, av.y, av.z, av.w};
            float b_[4] = {bv.x, bv.y, bv.z, bv.w};
#pragma unroll
            for (int i = 0; i < 4; i++)
#pragma unroll
                for (int j = 0; j < 4; j++) c[i][j] += a_[i] * b_[j];
        }
        __syncthreads();
    }

#pragma unroll
    for (int i = 0; i < 4; i++) {
        int gm = m0 + ty * 4 + i;
        if (gm >= M) continue;
        int gn = n0 + tx * 4;
        float4 v = make_float4(c[i][0], c[i][1], c[i][2], c[i][3]);
        if (EPI) {
            v.x = fmaxf(v.x + bias[gn + 0], 0.f);
            v.y = fmaxf(v.y + bias[gn + 1], 0.f);
            v.z = fmaxf(v.z + bias[gn + 2], 0.f);
            v.w = fmaxf(v.w + bias[gn + 3], 0.f);
        }
        *(float4*)(C + (long)gm * N + gn) = v;
    }
}

// ---------------- channel mean pooling ----------------
__global__ void pool_kernel(const float* h1, const float* h2, float* acc) {
    int ch = blockIdx.y;   // 0:t1 1:t2 2:s1 3:s2 4:g1 5:g2
    const float* p = ((ch & 1) ? h2 : h1) + (ch >> 1) * HSTRIDE;
    float s = 0.f;
    int nvec = HSTRIDE / 4;   // 151296
    for (int i = blockIdx.x * blockDim.x + threadIdx.x; i < nvec;
         i += gridDim.x * blockDim.x) {
        float4 v = *(const float4*)(p + (long)i * 4);
        s += v.x + v.y + v.z + v.w;
    }
#pragma unroll
    for (int off = 32; off > 0; off >>= 1) s += __shfl_down(s, off);
    if ((threadIdx.x & 63) == 0) atomicAdd(acc + ch, s);
}

// ---------------- tiny SE MLP: pool -> fc1 -> relu -> fc2 -> sigmoid, w=conv_w*a ----------------
__global__ void mlp_kernel(const float* acc, const float* fc1w, const float* fc1b,
                           const float* fc2w, const float* fc2b, const float* convw,
                           float* wout) {
    if (threadIdx.x != 0 || blockIdx.x != 0) return;
    float pool[6];
    const float inv = 1.0f / (float)HSTRIDE;
    for (int c = 0; c < 6; c++) pool[c] = acc[c] * inv;
    float h[30];
    for (int k = 0; k < 30; k++) {
        float s = fc1b[k];
        for (int c = 0; c < 6; c++) s += pool[c] * fc1w[k * 6 + c];
        h[k] = fmaxf(s, 0.f);
    }
    for (int j = 0; j < 6; j++) {
        float s = fc2b[j];
        for (int k = 0; k < 30; k++) s += h[k] * fc2w[j * 30 + k];
        float a = 1.0f / (1.0f + expf(-s));
        wout[j] = convw[j] * a;
    }
}

// ---------------- final weighted combine ----------------
__global__ void combine_kernel(const float* h1, const float* h2, const float* wv,
                               const float* convb, float* out) {
    int i = blockIdx.x * blockDim.x + threadIdx.x;
    const int nvec = HSTRIDE / 4;
    if (i >= nvec) return;
    float w0 = wv[0], w1 = wv[1], w2 = wv[2], w3 = wv[3], w4 = wv[4], w5 = wv[5];
    float cb = convb[0];
    long off = (long)i * 4;
    float4 a0 = *(const float4*)(h1 + off);
    float4 a1 = *(const float4*)(h2 + off);
    float4 a2 = *(const float4*)(h1 + HSTRIDE + off);
    float4 a3 = *(const float4*)(h2 + HSTRIDE + off);
    float4 a4 = *(const float4*)(h1 + 2 * HSTRIDE + off);
    float4 a5 = *(const float4*)(h2 + 2 * HSTRIDE + off);
    float4 r;
    r.x = cb + w0 * a0.x + w1 * a1.x + w2 * a2.x + w3 * a3.x + w4 * a4.x + w5 * a5.x;
    r.y = cb + w0 * a0.y + w1 * a1.y + w2 * a2.y + w3 * a3.y + w4 * a4.y + w5 * a5.y;
    r.z = cb + w0 * a0.z + w1 * a1.z + w2 * a2.z + w3 * a3.z + w4 * a4.z + w5 * a5.z;
    r.w = cb + w0 * a0.w + w1 * a1.w + w2 * a2.w + w3 * a3.w + w4 * a4.w + w5 * a5.w;
    *(float4*)(out + off) = r;
}

extern "C" void kernel_launch(void* const* d_in, const int* in_sizes, int n_in,
                              void* d_out, int out_size, void* d_ws, size_t ws_size,
                              hipStream_t stream) {
    const float* dm1 = (const float*)d_in[0];
    const int*   e_t = (const int*)d_in[1];
    const float* w_t = (const float*)d_in[2];
    const int*   e_s = (const int*)d_in[3];
    const float* w_s = (const float*)d_in[4];
    const int*   e_g = (const int*)d_in[5];
    const float* w_g = (const float*)d_in[6];
    const float* W_t1 = (const float*)d_in[7];
    const float* b_t1 = (const float*)d_in[8];
    const float* W_t2 = (const float*)d_in[9];
    const float* b_t2 = (const float*)d_in[10];
    const float* W_s1 = (const float*)d_in[11];
    const float* b_s1 = (const float*)d_in[12];
    const float* W_s2 = (const float*)d_in[13];
    const float* b_s2 = (const float*)d_in[14];
    const float* W_g1 = (const float*)d_in[15];
    const float* b_g1 = (const float*)d_in[16];
    const float* W_g2 = (const float*)d_in[17];
    const float* b_g2 = (const float*)d_in[18];
    const float* fc1w = (const float*)d_in[19];
    const float* fc1b = (const float*)d_in[20];
    const float* fc2w = (const float*)d_in[21];
    const float* fc2b = (const float*)d_in[22];
    const float* convw = (const float*)d_in[23];
    const float* convb = (const float*)d_in[24];
    float* out = (float*)d_out;
    float* ws = (float*)d_ws;

    float* deg  = ws;                    // 3*591 (alloc 2048)
    float* dinv = ws + 2048;             // 3*591 (alloc 2048)
    float* Amat = ws + 4096;             // 3*349281 (alloc 1048576)
    float* xw   = ws + 1052672;          // 3*605184
    float* h1   = xw + 3 * HSTRIDE;      // 3*605184
    float* h2   = h1 + 3 * HSTRIDE;      // 3*605184
    float* scal = h2 + 3 * HSTRIDE;      // acc[6] @0, w[6] @8

    const int S = HSTRIDE, AS = ASTRIDE;

    init_kernel<<<(3 * AS + 255) / 256, 256, 0, stream>>>(deg, Amat, scal);
    deg_kernel<<<(3 * NEDGE + 255) / 256, 256, 0, stream>>>(e_t, w_t, e_s, w_s, e_g, w_g, deg);
    dinv_kernel<<<(3 * NDRUG + 255) / 256, 256, 0, stream>>>(deg, dinv);
    abuild_kernel<<<(3 * (NEDGE + NDRUG) + 255) / 256, 256, 0, stream>>>(
        e_t, w_t, e_s, w_s, e_g, w_g, dinv, Amat);

    dim3 gg(FDIM / 64, (NDRUG + 63) / 64, 3);
    const float* nul = nullptr;

    // stage 1: xw = dm1 @ W1
    gemm_kernel<false><<<gg, 256, 0, stream>>>(
        dm1, dm1, dm1, FDIM, W_t1, W_s1, W_g1, nul, nul, nul,
        xw, xw + S, xw + 2 * S, NDRUG, FDIM, FDIM);
    // agg 1: h1 = relu(A @ xw + b1)
    gemm_kernel<true><<<gg, 256, 0, stream>>>(
        Amat, Amat + AS, Amat + 2 * AS, NDRUG, xw, xw + S, xw + 2 * S,
        b_t1, b_s1, b_g1, h1, h1 + S, h1 + 2 * S, NDRUG, NDRUG, FDIM);
    // stage 2: xw = h1 @ W2
    gemm_kernel<false><<<gg, 256, 0, stream>>>(
        h1, h1 + S, h1 + 2 * S, FDIM, W_t2, W_s2, W_g2, nul, nul, nul,
        xw, xw + S, xw + 2 * S, NDRUG, FDIM, FDIM);
    // agg 2: h2 = relu(A @ xw + b2)
    gemm_kernel<true><<<gg, 256, 0, stream>>>(
        Amat, Amat + AS, Amat + 2 * AS, NDRUG, xw, xw + S, xw + 2 * S,
        b_t2, b_s2, b_g2, h2, h2 + S, h2 + 2 * S, NDRUG, NDRUG, FDIM);

    pool_kernel<<<dim3(64, 6), 256, 0, stream>>>(h1, h2, scal);
    mlp_kernel<<<1, 64, 0, stream>>>(scal, fc1w, fc1b, fc2w, fc2b, convw, scal + 8);
    combine_kernel<<<(S / 4 + 255) / 256, 256, 0, stream>>>(h1, h2, scal + 8, convb, out);
}

// Round 3
// 282.516 us; speedup vs baseline: 1.7924x; 1.7924x over previous
//
#include <hip/hip_runtime.h>

#define NDRUG 591
#define FDIM 1024
#define NEDGE 120000
#define MPAD 640
#define ASTRIDE 349281          // 591*591 (fp32 temp adjacency)
#define ABSTRIDE (MPAD*MPAD)    // 409600  (bf16 padded adjacency)
#define HSTRIDE (MPAD*FDIM)     // 655360  (bf16 padded node features)
#define REAL (NDRUG*FDIM)       // 605184  real (row-contiguous) elements
#define WSTRIDE (FDIM*FDIM)     // 1048576

typedef __attribute__((ext_vector_type(8))) short bf16x8;
typedef __attribute__((ext_vector_type(4))) float f32x4;
typedef __attribute__((ext_vector_type(4))) unsigned short u16x4;

static __device__ __forceinline__ unsigned short f2bf(float f) {
    unsigned u = __builtin_bit_cast(unsigned, f);
    u += 0x7fffu + ((u >> 16) & 1u);            // RNE
    return (unsigned short)(u >> 16);
}
static __device__ __forceinline__ float bf2f(unsigned short h) {
    return __builtin_bit_cast(float, ((unsigned)h) << 16);
}

typedef const __attribute__((address_space(1))) unsigned int* gp1_t;
typedef __attribute__((address_space(3))) unsigned int* lp3_t;
static __device__ __forceinline__ void gload16(const void* g, unsigned short* l) {
    __builtin_amdgcn_global_load_lds((gp1_t)g, (lp3_t)l, 16, 0, 0);
}

// ---------------- init: zero fp32 A, deg=1 (self loop), zero pool acc ----------------
__global__ void init_kernel(float* deg, float* AmatF, float* scal) {
    int i = blockIdx.x * blockDim.x + threadIdx.x;
    if (i < 3 * ASTRIDE) AmatF[i] = 0.f;
    if (i < 3 * NDRUG) deg[i] = 1.0f;
    if (i < 16) scal[i] = 0.f;
}

__global__ void deg_kernel(const int* e_t, const float* w_t,
                           const int* e_s, const float* w_s,
                           const int* e_g, const float* w_g, float* deg) {
    int i = blockIdx.x * blockDim.x + threadIdx.x;
    if (i >= 3 * NEDGE) return;
    int g = i / NEDGE, e = i - g * NEDGE;
    const int*   E_ = (g == 0) ? e_t : (g == 1) ? e_s : e_g;
    const float* W_ = (g == 0) ? w_t : (g == 1) ? w_s : w_g;
    atomicAdd(deg + g * NDRUG + E_[NEDGE + e], W_[e]);
}

__global__ void dinv_kernel(const float* deg, float* dinv) {
    int i = blockIdx.x * blockDim.x + threadIdx.x;
    if (i >= 3 * NDRUG) return;
    float d = deg[i];
    dinv[i] = (d > 0.f) ? rsqrtf(d) : 0.f;
}

__global__ void abuild_kernel(const int* e_t, const float* w_t,
                              const int* e_s, const float* w_s,
                              const int* e_g, const float* w_g,
                              const float* dinv, float* AmatF) {
    int i = blockIdx.x * blockDim.x + threadIdx.x;
    const int PER = NEDGE + NDRUG;
    if (i >= 3 * PER) return;
    int g = i / PER, r = i - g * PER;
    const float* dv = dinv + g * NDRUG;
    float* Ag = AmatF + (long)g * ASTRIDE;
    if (r < NEDGE) {
        const int*   E_ = (g == 0) ? e_t : (g == 1) ? e_s : e_g;
        const float* W_ = (g == 0) ? w_t : (g == 1) ? w_s : w_g;
        int src = E_[r], dst = E_[NEDGE + r];
        atomicAdd(Ag + (long)dst * NDRUG + src, dv[src] * W_[r] * dv[dst]);
    } else {
        int n = r - NEDGE;
        atomicAdd(Ag + (long)n * NDRUG + n, dv[n] * dv[n]);
    }
}

// ---------------- conversions ----------------
// AmatF [591][591] fp32 -> Amatb [640][640] bf16, zero-padded
__global__ void conv_A(const float* AmatF, unsigned short* Amatb) {
    int r = blockIdx.x, g = blockIdx.y;
    int t = threadIdx.x;
    if (t >= 160) return;
    int c = t * 4;
    const float* src = AmatF + (long)g * ASTRIDE + (long)r * NDRUG;
    u16x4 o = {0, 0, 0, 0};
    if (r < NDRUG) {
#pragma unroll
        for (int j = 0; j < 4; j++) {
            int cc = c + j;
            if (cc < NDRUG) o[j] = f2bf(src[cc]);
        }
    }
    *(u16x4*)(Amatb + (long)g * ABSTRIDE + (long)r * MPAD + c) = o;
}

// dm1 [591][1024] fp32 -> dm1b [640][1024] bf16, zero-padded
__global__ void conv_dm1(const float* dm1, unsigned short* dm1b) {
    int r = blockIdx.x;
    int c = threadIdx.x * 4;
    u16x4 o = {0, 0, 0, 0};
    if (r < NDRUG) {
        float4 v = *(const float4*)(dm1 + (long)r * FDIM + c);
        o[0] = f2bf(v.x); o[1] = f2bf(v.y); o[2] = f2bf(v.z); o[3] = f2bf(v.w);
    }
    *(u16x4*)(dm1b + (long)r * FDIM + c) = o;
}

// W [K][N] fp32 -> WT [N][K] bf16, 3 matrices per call
__global__ void conv_w3(const float* w0, const float* w1, const float* w2,
                        unsigned short* WTb) {
    __shared__ float s[32][33];
    int z = blockIdx.z;
    const float* W = (z == 0) ? w0 : (z == 1) ? w1 : w2;
    unsigned short* WT = WTb + (long)z * WSTRIDE;
    int n0 = blockIdx.x * 32, k0 = blockIdx.y * 32;
    int tx = threadIdx.x & 31, ty = threadIdx.x >> 5;   // ty 0..7
#pragma unroll
    for (int p = 0; p < 4; p++)
        s[ty + 8 * p][tx] = W[(long)(k0 + ty + 8 * p) * FDIM + n0 + tx];
    __syncthreads();
#pragma unroll
    for (int p = 0; p < 4; p++)
        WT[(long)(n0 + ty + 8 * p) * FDIM + k0 + tx] = f2bf(s[tx][ty + 8 * p]);
}

// ---------------- bf16 MFMA GEMM ----------------
// C[m][n] = sum_k A[m][k] * BT[n][k]   (A: [Mpad][ldaK], BT: [N][ldbK], both bf16)
// EPI=0: store C transposed bf16 (C[n][m], ldC=MPAD), no epilogue
// EPI=1: store C normal bf16 (ldC=FDIM) with +bias, relu
template <int EPI>
__global__ __launch_bounds__(256) void mfma_gemm(
    const unsigned short* __restrict__ Abase, long strideA, int ldaK,
    const unsigned short* __restrict__ Bbase, long strideB, int ldbK,
    const float* __restrict__ bias0, const float* __restrict__ bias1,
    const float* __restrict__ bias2,
    unsigned short* __restrict__ Cbase, long strideC, int ldC, int K)
{
    __shared__ unsigned short ldsA[2][4096];
    __shared__ unsigned short ldsB[2][4096];

    const int g = blockIdx.z;
    const unsigned short* A = Abase + (long)g * strideA;
    const unsigned short* B = Bbase + (long)g * strideB;
    unsigned short* C = Cbase + (long)g * strideC;
    const float* bias = (g == 0) ? bias0 : (g == 1) ? bias1 : bias2;

    const int m0 = blockIdx.y * 64;
    const int n0 = blockIdx.x * 64;
    const int tid = threadIdx.x;
    const int w = tid >> 6, lane = tid & 63;
    const int l15 = lane & 15, lq = lane >> 4;
    const int wm = w >> 1, wn = w & 1;

    // staging geometry: seg = 2w or 2w+1 covers tile rows [8*seg, 8*seg+8)
    const int sr  = lane >> 3;                  // row within segment
    const int kcs = 8 * ((lane & 7) ^ sr);      // pre-swizzled k element offset
    const int segA0 = 2 * w, segA1 = 2 * w + 1;
    const int rA0 = segA0 * 8 + sr, rA1 = segA1 * 8 + sr;

    // fragment ds_read offsets (elements), swizzled to match staging
    int offA[2][2], offB[2][2];
    {
        int ra0 = 32 * wm + l15, ra1 = ra0 + 16;
        int rb0 = 32 * wn + l15, rb1 = rb0 + 16;
        offA[0][0] = ra0 * 64 + ((lq    ) ^ (ra0 & 7)) * 8;
        offA[0][1] = ra0 * 64 + ((lq + 4) ^ (ra0 & 7)) * 8;
        offA[1][0] = ra1 * 64 + ((lq    ) ^ (ra1 & 7)) * 8;
        offA[1][1] = ra1 * 64 + ((lq + 4) ^ (ra1 & 7)) * 8;
        offB[0][0] = rb0 * 64 + ((lq    ) ^ (rb0 & 7)) * 8;
        offB[0][1] = rb0 * 64 + ((lq + 4) ^ (rb0 & 7)) * 8;
        offB[1][0] = rb1 * 64 + ((lq    ) ^ (rb1 & 7)) * 8;
        offB[1][1] = rb1 * 64 + ((lq + 4) ^ (rb1 & 7)) * 8;
    }

    f32x4 acc00 = {0.f, 0.f, 0.f, 0.f}, acc01 = {0.f, 0.f, 0.f, 0.f};
    f32x4 acc10 = {0.f, 0.f, 0.f, 0.f}, acc11 = {0.f, 0.f, 0.f, 0.f};

    const int nt = K >> 6;

#define STAGE(bf, k0c) do {                                                        \
    gload16(A + (long)(m0 + rA0) * ldaK + (k0c) + kcs, &ldsA[bf][segA0 * 512]);    \
    gload16(A + (long)(m0 + rA1) * ldaK + (k0c) + kcs, &ldsA[bf][segA1 * 512]);    \
    gload16(B + (long)(n0 + rA0) * ldbK + (k0c) + kcs, &ldsB[bf][segA0 * 512]);    \
    gload16(B + (long)(n0 + rA1) * ldbK + (k0c) + kcs, &ldsB[bf][segA1 * 512]);    \
} while (0)

    STAGE(0, 0);
    __syncthreads();

    for (int t = 0; t < nt; ++t) {
        const int cur = t & 1;
        if (t + 1 < nt) STAGE(cur ^ 1, (t + 1) << 6);
        const unsigned short* pa = ldsA[cur];
        const unsigned short* pb = ldsB[cur];
        {
            bf16x8 a0 = *(const bf16x8*)(pa + offA[0][0]);
            bf16x8 a1 = *(const bf16x8*)(pa + offA[1][0]);
            bf16x8 b0 = *(const bf16x8*)(pb + offB[0][0]);
            bf16x8 b1 = *(const bf16x8*)(pb + offB[1][0]);
            acc00 = __builtin_amdgcn_mfma_f32_16x16x32_bf16(a0, b0, acc00, 0, 0, 0);
            acc01 = __builtin_amdgcn_mfma_f32_16x16x32_bf16(a0, b1, acc01, 0, 0, 0);
            acc10 = __builtin_amdgcn_mfma_f32_16x16x32_bf16(a1, b0, acc10, 0, 0, 0);
            acc11 = __builtin_amdgcn_mfma_f32_16x16x32_bf16(a1, b1, acc11, 0, 0, 0);
        }
        {
            bf16x8 a0 = *(const bf16x8*)(pa + offA[0][1]);
            bf16x8 a1 = *(const bf16x8*)(pa + offA[1][1]);
            bf16x8 b0 = *(const bf16x8*)(pb + offB[0][1]);
            bf16x8 b1 = *(const bf16x8*)(pb + offB[1][1]);
            acc00 = __builtin_amdgcn_mfma_f32_16x16x32_bf16(a0, b0, acc00, 0, 0, 0);
            acc01 = __builtin_amdgcn_mfma_f32_16x16x32_bf16(a0, b1, acc01, 0, 0, 0);
            acc10 = __builtin_amdgcn_mfma_f32_16x16x32_bf16(a1, b0, acc10, 0, 0, 0);
            acc11 = __builtin_amdgcn_mfma_f32_16x16x32_bf16(a1, b1, acc11, 0, 0, 0);
        }
        __syncthreads();
    }
#undef STAGE

    // epilogue: D layout col=lane&15, row=(lane>>4)*4+reg   [m89-verified]
    if (EPI == 0) {
#define TSTORE(accv, mo, no) do {                                   \
        int nn = n0 + 32 * wn + (no) * 16 + l15;                    \
        int mm = m0 + 32 * wm + (mo) * 16 + lq * 4;                 \
        u16x4 pk;                                                   \
        pk[0] = f2bf(accv[0]); pk[1] = f2bf(accv[1]);               \
        pk[2] = f2bf(accv[2]); pk[3] = f2bf(accv[3]);               \
        *(u16x4*)&C[(long)nn * ldC + mm] = pk;                      \
} while (0)
        TSTORE(acc00, 0, 0); TSTORE(acc01, 0, 1);
        TSTORE(acc10, 1, 0); TSTORE(acc11, 1, 1);
#undef TSTORE
    } else {
#define NSTORE(accv, mo, no) do {                                   \
        int nn = n0 + 32 * wn + (no) * 16 + l15;                    \
        int mm = m0 + 32 * wm + (mo) * 16 + lq * 4;                 \
        float bs = bias[nn];                                        \
        C[(long)(mm + 0) * ldC + nn] = f2bf(fmaxf(accv[0] + bs, 0.f)); \
        C[(long)(mm + 1) * ldC + nn] = f2bf(fmaxf(accv[1] + bs, 0.f)); \
        C[(long)(mm + 2) * ldC + nn] = f2bf(fmaxf(accv[2] + bs, 0.f)); \
        C[(long)(mm + 3) * ldC + nn] = f2bf(fmaxf(accv[3] + bs, 0.f)); \
} while (0)
        NSTORE(acc00, 0, 0); NSTORE(acc01, 0, 1);
        NSTORE(acc10, 1, 0); NSTORE(acc11, 1, 1);
#undef NSTORE
    }
}

// ---------------- pooling over bf16 channels ----------------
__global__ void pool_kernel(const unsigned short* h1b, const unsigned short* h2b,
                            float* acc) {
    int ch = blockIdx.y;
    const unsigned short* p = ((ch & 1) ? h2b : h1b) + (long)(ch >> 1) * HSTRIDE;
    const int nv = REAL / 8;
    float s = 0.f;
    for (int i = blockIdx.x * blockDim.x + threadIdx.x; i < nv;
         i += gridDim.x * blockDim.x) {
        bf16x8 v = *(const bf16x8*)(p + (long)i * 8);
#pragma unroll
        for (int j = 0; j < 8; j++) s += bf2f((unsigned short)v[j]);
    }
#pragma unroll
    for (int off = 32; off > 0; off >>= 1) s += __shfl_down(s, off);
    if ((threadIdx.x & 63) == 0) atomicAdd(acc + ch, s);
}

__global__ void mlp_kernel(const float* acc, const float* fc1w, const float* fc1b,
                           const float* fc2w, const float* fc2b, const float* convw,
                           float* wout) {
    if (threadIdx.x != 0 || blockIdx.x != 0) return;
    float pool[6];
    const float inv = 1.0f / (float)REAL;
    for (int c = 0; c < 6; c++) pool[c] = acc[c] * inv;
    float h[30];
    for (int k = 0; k < 30; k++) {
        float s = fc1b[k];
        for (int c = 0; c < 6; c++) s += pool[c] * fc1w[k * 6 + c];
        h[k] = fmaxf(s, 0.f);
    }
    for (int j = 0; j < 6; j++) {
        float s = fc2b[j];
        for (int k = 0; k < 30; k++) s += h[k] * fc2w[j * 30 + k];
        float a = 1.0f / (1.0f + expf(-s));
        wout[j] = convw[j] * a;
    }
}

__global__ void combine_kernel(const unsigned short* h1b, const unsigned short* h2b,
                               const float* wv, const float* convb, float* out) {
    int i = blockIdx.x * 256 + threadIdx.x;
    const int nv = REAL / 8;
    if (i >= nv) return;
    float cb = convb[0];
    float r[8];
#pragma unroll
    for (int j = 0; j < 8; j++) r[j] = cb;
#define ACCCH(c, ptr) do {                                          \
        float wc = wv[c];                                           \
        bf16x8 v = *(const bf16x8*)((ptr) + (long)i * 8);           \
        _Pragma("unroll")                                           \
        for (int j = 0; j < 8; j++) r[j] += wc * bf2f((unsigned short)v[j]); \
} while (0)
    ACCCH(0, h1b);
    ACCCH(1, h2b);
    ACCCH(2, h1b + HSTRIDE);
    ACCCH(3, h2b + HSTRIDE);
    ACCCH(4, h1b + 2 * HSTRIDE);
    ACCCH(5, h2b + 2 * HSTRIDE);
#undef ACCCH
    float4 o0 = make_float4(r[0], r[1], r[2], r[3]);
    float4 o1 = make_float4(r[4], r[5], r[6], r[7]);
    *(float4*)(out + (long)i * 8) = o0;
    *(float4*)(out + (long)i * 8 + 4) = o1;
}

extern "C" void kernel_launch(void* const* d_in, const int* in_sizes, int n_in,
                              void* d_out, int out_size, void* d_ws, size_t ws_size,
                              hipStream_t stream) {
    const float* dm1 = (const float*)d_in[0];
    const int*   e_t = (const int*)d_in[1];
    const float* w_t = (const float*)d_in[2];
    const int*   e_s = (const int*)d_in[3];
    const float* w_s = (const float*)d_in[4];
    const int*   e_g = (const int*)d_in[5];
    const float* w_g = (const float*)d_in[6];
    const float* W_t1 = (const float*)d_in[7];
    const float* b_t1 = (const float*)d_in[8];
    const float* W_t2 = (const float*)d_in[9];
    const float* b_t2 = (const float*)d_in[10];
    const float* W_s1 = (const float*)d_in[11];
    const float* b_s1 = (const float*)d_in[12];
    const float* W_s2 = (const float*)d_in[13];
    const float* b_s2 = (const float*)d_in[14];
    const float* W_g1 = (const float*)d_in[15];
    const float* b_g1 = (const float*)d_in[16];
    const float* W_g2 = (const float*)d_in[17];
    const float* b_g2 = (const float*)d_in[18];
    const float* fc1w = (const float*)d_in[19];
    const float* fc1b = (const float*)d_in[20];
    const float* fc2w = (const float*)d_in[21];
    const float* fc2b = (const float*)d_in[22];
    const float* convw = (const float*)d_in[23];
    const float* convb = (const float*)d_in[24];
    float* out = (float*)d_out;

    // workspace layout (bytes); fp32 adjacency aliases WTb (dead before conv_w3)
    char* base = (char*)d_ws;
    unsigned short* WTb = (unsigned short*)base;            // 3*1M bf16 = 6,291,456 B
    float* AmatF = (float*)base;                            // 3*349281*4 = 4,191,372 B (alias)
    size_t o = (size_t)3 * WSTRIDE * 2;
    float* deg  = (float*)(base + o); o += 8192;
    float* dinv = (float*)(base + o); o += 8192;
    float* scal = (float*)(base + o); o += 256;
    unsigned short* dm1b  = (unsigned short*)(base + o); o += (size_t)MPAD * FDIM * 2;
    unsigned short* Amatb = (unsigned short*)(base + o); o += (size_t)3 * ABSTRIDE * 2;
    unsigned short* xwT   = (unsigned short*)(base + o); o += (size_t)3 * HSTRIDE * 2;
    unsigned short* h1b   = (unsigned short*)(base + o); o += (size_t)3 * HSTRIDE * 2;
    unsigned short* h2b   = (unsigned short*)(base + o); o += (size_t)3 * HSTRIDE * 2;
    if (ws_size < o) return;   // refuse to fault if workspace too small

    // adjacency build (fp32) then convert; conv_w3 overwrites the alias afterwards
    init_kernel<<<(3 * ASTRIDE + 255) / 256, 256, 0, stream>>>(deg, AmatF, scal);
    deg_kernel<<<(3 * NEDGE + 255) / 256, 256, 0, stream>>>(e_t, w_t, e_s, w_s, e_g, w_g, deg);
    dinv_kernel<<<(3 * NDRUG + 255) / 256, 256, 0, stream>>>(deg, dinv);
    abuild_kernel<<<(3 * (NEDGE + NDRUG) + 255) / 256, 256, 0, stream>>>(
        e_t, w_t, e_s, w_s, e_g, w_g, dinv, AmatF);
    conv_A<<<dim3(MPAD, 3), 256, 0, stream>>>(AmatF, Amatb);
    conv_w3<<<dim3(32, 32, 3), 256, 0, stream>>>(W_t1, W_s1, W_g1, WTb);   // layer-1 set
    conv_dm1<<<MPAD, 256, 0, stream>>>(dm1, dm1b);

    dim3 gg(FDIM / 64, MPAD / 64, 3);
    // stage 1: xwT = (dm1b @ W1)^T
    mfma_gemm<0><<<gg, 256, 0, stream>>>(
        dm1b, 0L, FDIM, WTb, (long)WSTRIDE, FDIM,
        nullptr, nullptr, nullptr, xwT, (long)HSTRIDE, MPAD, FDIM);
    // layer-2 weight set conversion (reuses WTb; stage 1 is done with it)
    conv_w3<<<dim3(32, 32, 3), 256, 0, stream>>>(W_t2, W_s2, W_g2, WTb);
    // agg 1: h1 = relu(A @ xw + b1)
    mfma_gemm<1><<<gg, 256, 0, stream>>>(
        Amatb, (long)ABSTRIDE, MPAD, xwT, (long)HSTRIDE, MPAD,
        b_t1, b_s1, b_g1, h1b, (long)HSTRIDE, FDIM, MPAD);
    // stage 2: xwT = (h1 @ W2)^T
    mfma_gemm<0><<<gg, 256, 0, stream>>>(
        h1b, (long)HSTRIDE, FDIM, WTb, (long)WSTRIDE, FDIM,
        nullptr, nullptr, nullptr, xwT, (long)HSTRIDE, MPAD, FDIM);
    // agg 2: h2 = relu(A @ xw + b2)
    mfma_gemm<1><<<gg, 256, 0, stream>>>(
        Amatb, (long)ABSTRIDE, MPAD, xwT, (long)HSTRIDE, MPAD,
        b_t2, b_s2, b_g2, h2b, (long)HSTRIDE, FDIM, MPAD);

    pool_kernel<<<dim3(32, 6), 256, 0, stream>>>(h1b, h2b, scal);
    mlp_kernel<<<1, 64, 0, stream>>>(scal, fc1w, fc1b, fc2w, fc2b, convw, scal + 8);
    combine_kernel<<<(REAL / 8 + 255) / 256, 256, 0, stream>>>(h1b, h2b, scal + 8, convb, out);
}

// Round 4
// 217.982 us; speedup vs baseline: 2.3230x; 1.2961x over previous
//
#include <hip/hip_runtime.h>

#define NDRUG 591
#define FDIM 1024
#define NEDGE 120000
#define MPAD 640
#define ASTRIDE 349281          // 591*591 (fp32 temp adjacency, unnormalized)
#define ABSTRIDE (MPAD*MPAD)    // 409600  (bf16 padded adjacency)
#define HSTRIDE (MPAD*FDIM)     // 655360  (bf16 padded node features)
#define REAL (NDRUG*FDIM)       // 605184  real (row-contiguous) elements
#define WSTRIDE (FDIM*FDIM)     // 1048576

typedef __attribute__((ext_vector_type(8))) short bf16x8;
typedef __attribute__((ext_vector_type(4))) float f32x4;
typedef __attribute__((ext_vector_type(4))) unsigned short u16x4;

static __device__ __forceinline__ unsigned short f2bf(float f) {
    unsigned u = __builtin_bit_cast(unsigned, f);
    u += 0x7fffu + ((u >> 16) & 1u);            // RNE
    return (unsigned short)(u >> 16);
}
static __device__ __forceinline__ float bf2f(unsigned short h) {
    return __builtin_bit_cast(float, ((unsigned)h) << 16);
}

typedef const __attribute__((address_space(1))) unsigned int* gp1_t;
typedef __attribute__((address_space(3))) unsigned int* lp3_t;
static __device__ __forceinline__ void gload16(const void* g, unsigned short* l) {
    __builtin_amdgcn_global_load_lds((gp1_t)g, (lp3_t)l, 16, 0, 0);
}

// ---------------- init: zero fp32 A (vectorized), zero pool acc ----------------
__global__ void init_kernel(float* AmatF, float* scal) {
    int i = blockIdx.x * blockDim.x + threadIdx.x;
    const int TOT = 3 * ASTRIDE;
    int b = i * 4;
    if (b + 3 < TOT) {
        *(float4*)(AmatF + b) = make_float4(0.f, 0.f, 0.f, 0.f);
    } else if (b < TOT) {
        for (int j = b; j < TOT; ++j) AmatF[j] = 0.f;
    }
    if (i < 16) scal[i] = 0.f;
}

// ---------------- raw edge-weight scatter + self-loop (+1 on diagonal) ----------------
// Distinct-cell atomics: ~349k cells per graph -> negligible contention.
__global__ void scatter_kernel(const int* e_t, const float* w_t,
                               const int* e_s, const float* w_s,
                               const int* e_g, const float* w_g, float* AmatF) {
    int i = blockIdx.x * blockDim.x + threadIdx.x;
    const int PER = NEDGE + NDRUG;
    if (i >= 3 * PER) return;
    int g = i / PER, r = i - g * PER;
    float* Ag = AmatF + (long)g * ASTRIDE;
    if (r < NEDGE) {
        const int*   E_ = (g == 0) ? e_t : (g == 1) ? e_s : e_g;
        const float* W_ = (g == 0) ? w_t : (g == 1) ? w_s : w_g;
        int src = E_[r], dst = E_[NEDGE + r];
        atomicAdd(Ag + (long)dst * NDRUG + src, W_[r]);
    } else {
        int n = r - NEDGE;
        atomicAdd(Ag + (long)n * NDRUG + n, 1.0f);      // self-loop weight 1
    }
}

// ---------------- deg = rowsum(A); dinv = rsqrt(deg) ----------------
// One 64-lane wave per (row, graph). A is L2-resident (4.2 MB just written).
__global__ void rowdeg_kernel(const float* AmatF, float* dinv) {
    int r = blockIdx.x, g = blockIdx.y;
    const float* row = AmatF + (long)g * ASTRIDE + (long)r * NDRUG;
    float s = 0.f;
    for (int c = threadIdx.x; c < NDRUG; c += 64) s += row[c];
#pragma unroll
    for (int off = 32; off > 0; off >>= 1) s += __shfl_down(s, off);
    if (threadIdx.x == 0)
        dinv[g * NDRUG + r] = (s > 0.f) ? rsqrtf(s) : 0.f;
}

// ---------------- fused normalize + bf16 convert + pad ----------------
// Amatb[r][c] = bf16( dinv[c] * A[r][c] * dinv[r] ), zero-padded to 640x640
__global__ void conv_A(const float* AmatF, const float* dinv, unsigned short* Amatb) {
    int r = blockIdx.x, g = blockIdx.y;
    int t = threadIdx.x;
    if (t >= 160) return;
    int c = t * 4;
    u16x4 o = {0, 0, 0, 0};
    if (r < NDRUG) {
        const float* src = AmatF + (long)g * ASTRIDE + (long)r * NDRUG;
        const float* dv = dinv + g * NDRUG;
        float dr = dv[r];
#pragma unroll
        for (int j = 0; j < 4; j++) {
            int cc = c + j;
            if (cc < NDRUG) o[j] = f2bf(src[cc] * dv[cc] * dr);
        }
    }
    *(u16x4*)(Amatb + (long)g * ABSTRIDE + (long)r * MPAD + c) = o;
}

// dm1 [591][1024] fp32 -> dm1b [640][1024] bf16, zero-padded
__global__ void conv_dm1(const float* dm1, unsigned short* dm1b) {
    int r = blockIdx.x;
    int c = threadIdx.x * 4;
    u16x4 o = {0, 0, 0, 0};
    if (r < NDRUG) {
        float4 v = *(const float4*)(dm1 + (long)r * FDIM + c);
        o[0] = f2bf(v.x); o[1] = f2bf(v.y); o[2] = f2bf(v.z); o[3] = f2bf(v.w);
    }
    *(u16x4*)(dm1b + (long)r * FDIM + c) = o;
}

// W [K][N] fp32 -> WT [N][K] bf16, all 6 matrices (order t1,s1,g1,t2,s2,g2)
__global__ void conv_w6(const float* w0, const float* w1, const float* w2,
                        const float* w3, const float* w4, const float* w5,
                        unsigned short* WTb) {
    __shared__ float s[32][33];
    int z = blockIdx.z;
    const float* W = (z == 0) ? w0 : (z == 1) ? w1 : (z == 2) ? w2
                   : (z == 3) ? w3 : (z == 4) ? w4 : w5;
    unsigned short* WT = WTb + (long)z * WSTRIDE;
    int n0 = blockIdx.x * 32, k0 = blockIdx.y * 32;
    int tx = threadIdx.x & 31, ty = threadIdx.x >> 5;   // ty 0..7
#pragma unroll
    for (int p = 0; p < 4; p++)
        s[ty + 8 * p][tx] = W[(long)(k0 + ty + 8 * p) * FDIM + n0 + tx];
    __syncthreads();
#pragma unroll
    for (int p = 0; p < 4; p++)
        WT[(long)(n0 + ty + 8 * p) * FDIM + k0 + tx] = f2bf(s[tx][ty + 8 * p]);
}

// ---------------- bf16 MFMA GEMM ----------------
// C[m][n] = sum_k A[m][k] * BT[n][k]   (A: [Mpad][ldaK], BT: [N][ldbK], both bf16)
// EPI=0: store C transposed bf16 (C[n][m], ldC=MPAD), no epilogue
// EPI=1: store C normal bf16 (ldC=FDIM) with +bias, relu
template <int EPI>
__global__ __launch_bounds__(256) void mfma_gemm(
    const unsigned short* __restrict__ Abase, long strideA, int ldaK,
    const unsigned short* __restrict__ Bbase, long strideB, int ldbK,
    const float* __restrict__ bias0, const float* __restrict__ bias1,
    const float* __restrict__ bias2,
    unsigned short* __restrict__ Cbase, long strideC, int ldC, int K)
{
    __shared__ unsigned short ldsA[2][4096];
    __shared__ unsigned short ldsB[2][4096];

    const int g = blockIdx.z;
    const unsigned short* A = Abase + (long)g * strideA;
    const unsigned short* B = Bbase + (long)g * strideB;
    unsigned short* C = Cbase + (long)g * strideC;
    const float* bias = (g == 0) ? bias0 : (g == 1) ? bias1 : bias2;

    const int m0 = blockIdx.y * 64;
    const int n0 = blockIdx.x * 64;
    const int tid = threadIdx.x;
    const int w = tid >> 6, lane = tid & 63;
    const int l15 = lane & 15, lq = lane >> 4;
    const int wm = w >> 1, wn = w & 1;

    // staging geometry: seg = 2w or 2w+1 covers tile rows [8*seg, 8*seg+8)
    const int sr  = lane >> 3;                  // row within segment
    const int kcs = 8 * ((lane & 7) ^ sr);      // pre-swizzled k element offset
    const int segA0 = 2 * w, segA1 = 2 * w + 1;
    const int rA0 = segA0 * 8 + sr, rA1 = segA1 * 8 + sr;

    // fragment ds_read offsets (elements), swizzled to match staging
    int offA[2][2], offB[2][2];
    {
        int ra0 = 32 * wm + l15, ra1 = ra0 + 16;
        int rb0 = 32 * wn + l15, rb1 = rb0 + 16;
        offA[0][0] = ra0 * 64 + ((lq    ) ^ (ra0 & 7)) * 8;
        offA[0][1] = ra0 * 64 + ((lq + 4) ^ (ra0 & 7)) * 8;
        offA[1][0] = ra1 * 64 + ((lq    ) ^ (ra1 & 7)) * 8;
        offA[1][1] = ra1 * 64 + ((lq + 4) ^ (ra1 & 7)) * 8;
        offB[0][0] = rb0 * 64 + ((lq    ) ^ (rb0 & 7)) * 8;
        offB[0][1] = rb0 * 64 + ((lq + 4) ^ (rb0 & 7)) * 8;
        offB[1][0] = rb1 * 64 + ((lq    ) ^ (rb1 & 7)) * 8;
        offB[1][1] = rb1 * 64 + ((lq + 4) ^ (rb1 & 7)) * 8;
    }

    f32x4 acc00 = {0.f, 0.f, 0.f, 0.f}, acc01 = {0.f, 0.f, 0.f, 0.f};
    f32x4 acc10 = {0.f, 0.f, 0.f, 0.f}, acc11 = {0.f, 0.f, 0.f, 0.f};

    const int nt = K >> 6;

#define STAGE(bf, k0c) do {                                                        \
    gload16(A + (long)(m0 + rA0) * ldaK + (k0c) + kcs, &ldsA[bf][segA0 * 512]);    \
    gload16(A + (long)(m0 + rA1) * ldaK + (k0c) + kcs, &ldsA[bf][segA1 * 512]);    \
    gload16(B + (long)(n0 + rA0) * ldbK + (k0c) + kcs, &ldsB[bf][segA0 * 512]);    \
    gload16(B + (long)(n0 + rA1) * ldbK + (k0c) + kcs, &ldsB[bf][segA1 * 512]);    \
} while (0)

    STAGE(0, 0);
    __syncthreads();

    for (int t = 0; t < nt; ++t) {
        const int cur = t & 1;
        if (t + 1 < nt) STAGE(cur ^ 1, (t + 1) << 6);
        const unsigned short* pa = ldsA[cur];
        const unsigned short* pb = ldsB[cur];
        {
            bf16x8 a0 = *(const bf16x8*)(pa + offA[0][0]);
            bf16x8 a1 = *(const bf16x8*)(pa + offA[1][0]);
            bf16x8 b0 = *(const bf16x8*)(pb + offB[0][0]);
            bf16x8 b1 = *(const bf16x8*)(pb + offB[1][0]);
            acc00 = __builtin_amdgcn_mfma_f32_16x16x32_bf16(a0, b0, acc00, 0, 0, 0);
            acc01 = __builtin_amdgcn_mfma_f32_16x16x32_bf16(a0, b1, acc01, 0, 0, 0);
            acc10 = __builtin_amdgcn_mfma_f32_16x16x32_bf16(a1, b0, acc10, 0, 0, 0);
            acc11 = __builtin_amdgcn_mfma_f32_16x16x32_bf16(a1, b1, acc11, 0, 0, 0);
        }
        {
            bf16x8 a0 = *(const bf16x8*)(pa + offA[0][1]);
            bf16x8 a1 = *(const bf16x8*)(pa + offA[1][1]);
            bf16x8 b0 = *(const bf16x8*)(pb + offB[0][1]);
            bf16x8 b1 = *(const bf16x8*)(pb + offB[1][1]);
            acc00 = __builtin_amdgcn_mfma_f32_16x16x32_bf16(a0, b0, acc00, 0, 0, 0);
            acc01 = __builtin_amdgcn_mfma_f32_16x16x32_bf16(a0, b1, acc01, 0, 0, 0);
            acc10 = __builtin_amdgcn_mfma_f32_16x16x32_bf16(a1, b0, acc10, 0, 0, 0);
            acc11 = __builtin_amdgcn_mfma_f32_16x16x32_bf16(a1, b1, acc11, 0, 0, 0);
        }
        __syncthreads();
    }
#undef STAGE

    // epilogue: D layout col=lane&15, row=(lane>>4)*4+reg   [m89-verified]
    if (EPI == 0) {
#define TSTORE(accv, mo, no) do {                                   \
        int nn = n0 + 32 * wn + (no) * 16 + l15;                    \
        int mm = m0 + 32 * wm + (mo) * 16 + lq * 4;                 \
        u16x4 pk;                                                   \
        pk[0] = f2bf(accv[0]); pk[1] = f2bf(accv[1]);               \
        pk[2] = f2bf(accv[2]); pk[3] = f2bf(accv[3]);               \
        *(u16x4*)&C[(long)nn * ldC + mm] = pk;                      \
} while (0)
        TSTORE(acc00, 0, 0); TSTORE(acc01, 0, 1);
        TSTORE(acc10, 1, 0); TSTORE(acc11, 1, 1);
#undef TSTORE
    } else {
#define NSTORE(accv, mo, no) do {                                   \
        int nn = n0 + 32 * wn + (no) * 16 + l15;                    \
        int mm = m0 + 32 * wm + (mo) * 16 + lq * 4;                 \
        float bs = bias[nn];                                        \
        C[(long)(mm + 0) * ldC + nn] = f2bf(fmaxf(accv[0] + bs, 0.f)); \
        C[(long)(mm + 1) * ldC + nn] = f2bf(fmaxf(accv[1] + bs, 0.f)); \
        C[(long)(mm + 2) * ldC + nn] = f2bf(fmaxf(accv[2] + bs, 0.f)); \
        C[(long)(mm + 3) * ldC + nn] = f2bf(fmaxf(accv[3] + bs, 0.f)); \
} while (0)
        NSTORE(acc00, 0, 0); NSTORE(acc01, 0, 1);
        NSTORE(acc10, 1, 0); NSTORE(acc11, 1, 1);
#undef NSTORE
    }
}

// ---------------- pooling over bf16 channels ----------------
__global__ void pool_kernel(const unsigned short* h1b, const unsigned short* h2b,
                            float* acc) {
    int ch = blockIdx.y;
    const unsigned short* p = ((ch & 1) ? h2b : h1b) + (long)(ch >> 1) * HSTRIDE;
    const int nv = REAL / 8;
    float s = 0.f;
    for (int i = blockIdx.x * blockDim.x + threadIdx.x; i < nv;
         i += gridDim.x * blockDim.x) {
        bf16x8 v = *(const bf16x8*)(p + (long)i * 8);
#pragma unroll
        for (int j = 0; j < 8; j++) s += bf2f((unsigned short)v[j]);
    }
#pragma unroll
    for (int off = 32; off > 0; off >>= 1) s += __shfl_down(s, off);
    if ((threadIdx.x & 63) == 0) atomicAdd(acc + ch, s);
}

__global__ void mlp_kernel(const float* acc, const float* fc1w, const float* fc1b,
                           const float* fc2w, const float* fc2b, const float* convw,
                           float* wout) {
    if (threadIdx.x != 0 || blockIdx.x != 0) return;
    float pool[6];
    const float inv = 1.0f / (float)REAL;
    for (int c = 0; c < 6; c++) pool[c] = acc[c] * inv;
    float h[30];
    for (int k = 0; k < 30; k++) {
        float s = fc1b[k];
        for (int c = 0; c < 6; c++) s += pool[c] * fc1w[k * 6 + c];
        h[k] = fmaxf(s, 0.f);
    }
    for (int j = 0; j < 6; j++) {
        float s = fc2b[j];
        for (int k = 0; k < 30; k++) s += h[k] * fc2w[j * 30 + k];
        float a = 1.0f / (1.0f + expf(-s));
        wout[j] = convw[j] * a;
    }
}

__global__ void combine_kernel(const unsigned short* h1b, const unsigned short* h2b,
                               const float* wv, const float* convb, float* out) {
    int i = blockIdx.x * 256 + threadIdx.x;
    const int nv = REAL / 8;
    if (i >= nv) return;
    float cb = convb[0];
    float r[8];
#pragma unroll
    for (int j = 0; j < 8; j++) r[j] = cb;
#define ACCCH(c, ptr) do {                                          \
        float wc = wv[c];                                           \
        bf16x8 v = *(const bf16x8*)((ptr) + (long)i * 8);           \
        _Pragma("unroll")                                           \
        for (int j = 0; j < 8; j++) r[j] += wc * bf2f((unsigned short)v[j]); \
} while (0)
    ACCCH(0, h1b);
    ACCCH(1, h2b);
    ACCCH(2, h1b + HSTRIDE);
    ACCCH(3, h2b + HSTRIDE);
    ACCCH(4, h1b + 2 * HSTRIDE);
    ACCCH(5, h2b + 2 * HSTRIDE);
#undef ACCCH
    float4 o0 = make_float4(r[0], r[1], r[2], r[3]);
    float4 o1 = make_float4(r[4], r[5], r[6], r[7]);
    *(float4*)(out + (long)i * 8) = o0;
    *(float4*)(out + (long)i * 8 + 4) = o1;
}

extern "C" void kernel_launch(void* const* d_in, const int* in_sizes, int n_in,
                              void* d_out, int out_size, void* d_ws, size_t ws_size,
                              hipStream_t stream) {
    const float* dm1 = (const float*)d_in[0];
    const int*   e_t = (const int*)d_in[1];
    const float* w_t = (const float*)d_in[2];
    const int*   e_s = (const int*)d_in[3];
    const float* w_s = (const float*)d_in[4];
    const int*   e_g = (const int*)d_in[5];
    const float* w_g = (const float*)d_in[6];
    const float* W_t1 = (const float*)d_in[7];
    const float* b_t1 = (const float*)d_in[8];
    const float* W_t2 = (const float*)d_in[9];
    const float* b_t2 = (const float*)d_in[10];
    const float* W_s1 = (const float*)d_in[11];
    const float* b_s1 = (const float*)d_in[12];
    const float* W_s2 = (const float*)d_in[13];
    const float* b_s2 = (const float*)d_in[14];
    const float* W_g1 = (const float*)d_in[15];
    const float* b_g1 = (const float*)d_in[16];
    const float* W_g2 = (const float*)d_in[17];
    const float* b_g2 = (const float*)d_in[18];
    const float* fc1w = (const float*)d_in[19];
    const float* fc1b = (const float*)d_in[20];
    const float* fc2w = (const float*)d_in[21];
    const float* fc2b = (const float*)d_in[22];
    const float* convw = (const float*)d_in[23];
    const float* convb = (const float*)d_in[24];
    float* out = (float*)d_out;

    // workspace layout (bytes):
    //   WTb       : 6 weight mats bf16, 12,582,912 B
    //   AmatF     : fp32 adjacency 4,191,372 B — ALIASES WTb[0..] (dead before conv_w6)
    //   h2b       : ALIASES WTb layer-2 half (dead after stage-2 GEMM)
    char* base = (char*)d_ws;
    unsigned short* WTb = (unsigned short*)base;
    float* AmatF = (float*)base;
    unsigned short* h2b = (unsigned short*)(base + (size_t)3 * WSTRIDE * 2);
    size_t o = (size_t)6 * WSTRIDE * 2;
    float* dinv = (float*)(base + o); o += 8192;
    float* scal = (float*)(base + o); o += 256;
    unsigned short* dm1b  = (unsigned short*)(base + o); o += (size_t)MPAD * FDIM * 2;
    unsigned short* Amatb = (unsigned short*)(base + o); o += (size_t)3 * ABSTRIDE * 2;
    unsigned short* xwT   = (unsigned short*)(base + o); o += (size_t)3 * HSTRIDE * 2;
    unsigned short* h1b   = (unsigned short*)(base + o); o += (size_t)3 * HSTRIDE * 2;
    if (ws_size < o) return;   // refuse to fault if workspace too small (24.2 MB)

    // dense adjacency: zero -> raw scatter (+1 diag) -> rowsum deg -> normalize+bf16
    init_kernel<<<(3 * ASTRIDE / 4 + 256) / 256, 256, 0, stream>>>(AmatF, scal);
    scatter_kernel<<<(3 * (NEDGE + NDRUG) + 255) / 256, 256, 0, stream>>>(
        e_t, w_t, e_s, w_s, e_g, w_g, AmatF);
    rowdeg_kernel<<<dim3(NDRUG, 3), 64, 0, stream>>>(AmatF, dinv);
    conv_A<<<dim3(MPAD, 3), 256, 0, stream>>>(AmatF, dinv, Amatb);
    conv_w6<<<dim3(32, 32, 6), 256, 0, stream>>>(
        W_t1, W_s1, W_g1, W_t2, W_s2, W_g2, WTb);    // overwrites AmatF alias (dead)
    conv_dm1<<<MPAD, 256, 0, stream>>>(dm1, dm1b);

    dim3 gg(FDIM / 64, MPAD / 64, 3);
    // stage 1: xwT = (dm1b @ W1)^T
    mfma_gemm<0><<<gg, 256, 0, stream>>>(
        dm1b, 0L, FDIM, WTb, (long)WSTRIDE, FDIM,
        nullptr, nullptr, nullptr, xwT, (long)HSTRIDE, MPAD, FDIM);
    // agg 1: h1 = relu(A @ xw + b1)
    mfma_gemm<1><<<gg, 256, 0, stream>>>(
        Amatb, (long)ABSTRIDE, MPAD, xwT, (long)HSTRIDE, MPAD,
        b_t1, b_s1, b_g1, h1b, (long)HSTRIDE, FDIM, MPAD);
    // stage 2: xwT = (h1 @ W2)^T   (consumes WTb layer-2 half)
    mfma_gemm<0><<<gg, 256, 0, stream>>>(
        h1b, (long)HSTRIDE, FDIM, WTb + (size_t)3 * WSTRIDE, (long)WSTRIDE, FDIM,
        nullptr, nullptr, nullptr, xwT, (long)HSTRIDE, MPAD, FDIM);
    // agg 2: h2 = relu(A @ xw + b2)   (h2b aliases the now-dead WTb layer-2 half)
    mfma_gemm<1><<<gg, 256, 0, stream>>>(
        Amatb, (long)ABSTRIDE, MPAD, xwT, (long)HSTRIDE, MPAD,
        b_t2, b_s2, b_g2, h2b, (long)HSTRIDE, FDIM, MPAD);

    pool_kernel<<<dim3(32, 6), 256, 0, stream>>>(h1b, h2b, scal);
    mlp_kernel<<<1, 64, 0, stream>>>(scal, fc1w, fc1b, fc2w, fc2b, convw, scal + 8);
    combine_kernel<<<(REAL / 8 + 255) / 256, 256, 0, stream>>>(h1b, h2b, scal + 8, convb, out);
}